// Round 9
// baseline (231.160 us; speedup 1.0000x reference)
//
#include <hip/hip_runtime.h>
#include <hip/hip_bf16.h>
#include <stdint.h>

#define TSEQ 3072
#define DIMM 1024
#define NH   8
#define HD   128
#define QBLK 32
#define BM   1408
#define CHUNK 384
#define NQB  (TSEQ / QBLK)   // 96
#define NCMAX 5

typedef float f32x4 __attribute__((ext_vector_type(4)));
typedef short s16x8 __attribute__((ext_vector_type(8)));
typedef unsigned short u16;

// ---------- helpers ----------
static __device__ __forceinline__ u16 f2b(float f) {
  union { float f; unsigned u; } a; a.f = f;
  unsigned r = a.u + 0x7FFFu + ((a.u >> 16) & 1u);   // RNE
  return (u16)(r >> 16);
}
static __device__ __forceinline__ float b2f(u16 u) {
  union { unsigned u; float f; } a; a.u = ((unsigned)u) << 16;
  return a.f;
}
static __device__ __forceinline__ void gload_lds16(const void* g, void* l) {
  __builtin_amdgcn_global_load_lds(
      (const __attribute__((address_space(1))) unsigned int*)(unsigned long long)g,
      (__attribute__((address_space(3))) unsigned int*)(unsigned long long)l,
      16, 0, 0);
}
static __device__ __forceinline__ void bar() {
  asm volatile("" ::: "memory");
  __builtin_amdgcn_s_barrier();
  asm volatile("" ::: "memory");
}
#define SWAIT(n) asm volatile("s_waitcnt vmcnt(" #n ")" ::: "memory")
#define CFENCE() asm volatile("" ::: "memory")

// ---------- 0: f32 -> bf16 conversion (w scaled by sa_lambdas) ----------
__global__ __launch_bounds__(256) void k_convert(
    const float* __restrict__ x, const float* __restrict__ w,
    const float* __restrict__ lam,
    u16* __restrict__ xb, u16* __restrict__ wb)
{
  const int NX = TSEQ * DIMM;
  const int NW = 4 * DIMM * DIMM;
  const float l0 = lam[0], l1 = lam[1];
  const int n4 = (NX + NW) >> 2;
  for (int j = blockIdx.x * 256 + threadIdx.x; j < n4; j += gridDim.x * 256) {
    const int e = j << 2;
    float4 v; u16* dst; float s;
    if (e < NX) { v = *(const float4*)(x + e); dst = xb + e; s = 1.f; }
    else {
      const int we = e - NX;
      v = *(const float4*)(w + we);
      dst = wb + we;
      s = (we < 3 * DIMM * DIMM) ? l0 : l1;
    }
    dst[0] = f2b(v.x * s); dst[1] = f2b(v.y * s);
    dst[2] = f2b(v.z * s); dst[3] = f2b(v.w * s);
  }
}

// ---------- NT GEMM: C[M][N] = A[M][K] * B[N][K]^T  (bf16 in, f32 out) ----------
// double-buffered prefetch + XOR-swizzled LDS (proven round 7).
__global__ __launch_bounds__(256) void k_gemm_nt(
    const u16* __restrict__ A, const u16* __restrict__ B,
    float* __restrict__ C, int M, int N, int K)
{
  __shared__ u16 As[2][128 * 64];
  __shared__ u16 Bs[2][128 * 64];
  const int tid = threadIdx.x;
  const int lane = tid & 63, wv = tid >> 6;
  const int m0 = blockIdx.y * 128, n0 = blockIdx.x * 128;
  const int wm = (wv >> 1) * 64, wn = (wv & 1) * 64;
  const int c0 = lane & 15, r0 = (lane >> 4) * 4, koff = (lane >> 4) * 8;

  f32x4 acc[4][4];
  #pragma unroll
  for (int i = 0; i < 4; i++)
    #pragma unroll
    for (int j = 0; j < 4; j++) acc[i][j] = (f32x4){0.f, 0.f, 0.f, 0.f};

  const int srow  = tid >> 3;        // 0..31 (+ i*32)
  const int scolb = (tid & 7) * 16;  // byte offset within 128B row

  auto stage = [&](int buf, int kt) {
    #pragma unroll
    for (int i = 0; i < 4; i++) {
      const int row = srow + i * 32;
      const int scb = scolb ^ ((row & 7) << 4);   // inverse-swizzled source col (bytes)
      const int ldst = row * 128 + scolb;         // linear LDS dest
      gload_lds16(A + (size_t)(m0 + row) * K + kt + (scb >> 1), (char*)As[buf] + ldst);
      gload_lds16(B + (size_t)(n0 + row) * K + kt + (scb >> 1), (char*)Bs[buf] + ldst);
    }
  };

  stage(0, 0);
  int cur = 0;
  for (int kt = 0; kt < K; kt += 64) {
    if (kt + 64 < K) {
      stage(cur ^ 1, kt + 64);
      SWAIT(8);
    } else {
      SWAIT(0);
    }
    bar();

    #pragma unroll
    for (int kk = 0; kk < 2; kk++) {
      s16x8 af[4], bf[4];
      #pragma unroll
      for (int i = 0; i < 4; i++) {
        const int ar = wm + i * 16 + c0;
        const int br = wn + i * 16 + c0;
        const int cb = (kk * 32 + koff) * 2;
        af[i] = *(const s16x8*)((const char*)As[cur] + ar * 128 + (cb ^ ((ar & 7) << 4)));
        bf[i] = *(const s16x8*)((const char*)Bs[cur] + br * 128 + (cb ^ ((br & 7) << 4)));
      }
      #pragma unroll
      for (int i = 0; i < 4; i++)
        #pragma unroll
        for (int j = 0; j < 4; j++)
          acc[i][j] = __builtin_amdgcn_mfma_f32_16x16x32_bf16(af[i], bf[j], acc[i][j], 0, 0, 0);
    }

    bar();
    cur ^= 1;
  }

  #pragma unroll
  for (int i = 0; i < 4; i++)
    #pragma unroll
    for (int j = 0; j < 4; j++) {
      float* cp = C + (size_t)(m0 + wm + i * 16 + r0) * N + n0 + wn + j * 16 + c0;
      #pragma unroll
      for (int r = 0; r < 4; r++) cp[(size_t)r * N] = acc[i][j][r];
    }
}

// ---------- 2: fused prep v3. Block: 256 thr (4 waves), owns (h, 32 t-rows) ----------
// grid (96, 8) = 768 blocks -> 3 blocks/CU (was 1.5): 2x latency hiding for the
// serial shfl reduction chains.
__global__ __launch_bounds__(256) void k_prep(
    const float* __restrict__ qkv, const float* __restrict__ x,
    const float* __restrict__ ve, const float* __restrict__ cosb,
    const float* __restrict__ sinb, const float* __restrict__ gwa,
    const float* __restrict__ gwv, const int* __restrict__ seg,
    u16* __restrict__ Qg, u16* __restrict__ Kg, u16* __restrict__ VTg,
    float* __restrict__ gateA, int* __restrict__ segb)
{
  __shared__ u16 vtile[32][130];   // [t][d], padded stride
  const int tid = threadIdx.x;
  const int lane = tid & 63, w = tid >> 6;
  const int h = blockIdx.y;
  const int t0 = blockIdx.x * 32;

  if (h == 0 && t0 == 0 && tid == 0) {
    const int sv = seg[0];
    int lo = 1, hi = TSEQ;
    while (lo < hi) { const int mid = (lo + hi) >> 1; if (seg[mid] == sv) lo = mid + 1; else hi = mid; }
    segb[0] = lo;
  }

  #pragma unroll
  for (int it = 0; it < 8; ++it) {
    const int tt = it * 4 + w;
    const int t = t0 + tt;
    const int tp = (t == 0) ? 0 : t - 1;

    const float* qrow = qkv + (size_t)t * (3 * DIMM) + h * HD;
    const float* krow = qrow + DIMM;
    const float* vrow = qrow + 2 * DIMM;
    const float* prow = qkv + (size_t)tp * (3 * DIMM) + DIMM + h * HD;

    float q1 = qrow[lane], q2 = qrow[lane + 64];
    float k1 = krow[lane], k2 = krow[lane + 64];
    float p1 = prow[lane], p2 = prow[lane + 64];

    float sq = q1 * q1 + q2 * q2, sk = k1 * k1 + k2 * k2, sp = p1 * p1 + p2 * p2;
    #pragma unroll
    for (int m = 1; m < 64; m <<= 1) {
      sq += __shfl_xor(sq, m, 64);
      sk += __shfl_xor(sk, m, 64);
      sp += __shfl_xor(sp, m, 64);
    }
    const float rq = rsqrtf(sq * (1.f / 128.f) + 1e-6f);
    const float rk = rsqrtf(sk * (1.f / 128.f) + 1e-6f);
    const float rp = rsqrtf(sp * (1.f / 128.f) + 1e-6f);
    q1 *= rq; q2 *= rq; k1 *= rk; k2 *= rk; p1 *= rp; p2 *= rp;

    const float c  = cosb[t * 64 + lane],  s  = sinb[t * 64 + lane];
    const float cp = cosb[tp * 64 + lane], spv = sinb[tp * 64 + lane];
    const float qo1 =  q1 * c + q2 * s,   qo2 = -q1 * s + q2 * c;
    const float ko1 =  k1 * c + k2 * s,   ko2 = -k1 * s + k2 * c;
    const float po1 =  p1 * cp + p2 * spv, po2 = -p1 * spv + p2 * cp;
    const float m1 = (lane < 32) ? ko1 : po1;
    const float m2 = (lane < 32) ? ko2 : po2;

    const size_t qkbase = ((size_t)h * TSEQ + t) * HD + lane;
    Qg[qkbase] = f2b(qo1 * 0.1f); Qg[qkbase + 64] = f2b(qo2 * 0.1f);  // attn scale folded
    Kg[qkbase] = f2b(m1);  Kg[qkbase + 64] = f2b(m2);

    float dv = 0.f, da = 0.f;
    #pragma unroll
    for (int g = 0; g < 16; g++) {
      const float xv = x[(size_t)t * DIMM + g];
      dv += xv * gwv[h * 16 + g];
      da += xv * gwa[h * 16 + g];
    }
    const float vg = 2.f / (1.f + __expf(-dv));
    const float v1 = vrow[lane]      + vg * ve[(size_t)t * DIMM + h * HD + lane];
    const float v2 = vrow[lane + 64] + vg * ve[(size_t)t * DIMM + h * HD + lane + 64];
    vtile[tt][lane] = f2b(v1); vtile[tt][lane + 64] = f2b(v2);
    if (lane == 0) gateA[h * TSEQ + t] = 1.f / (1.f + __expf(-da));
  }
  __syncthreads();
  // transpose write-out: VT[h][d][t0..t0+31], 64B chunks per d-row
  #pragma unroll
  for (int rep = 0; rep < 2; ++rep) {
    const int d = rep * 64 + (tid >> 2);
    const int cc = (tid & 3) * 8;
    s16x8 v;
    #pragma unroll
    for (int j = 0; j < 8; j++) ((u16*)&v)[j] = vtile[cc + j][d];
    *(s16x8*)(VTg + ((size_t)h * HD + d) * TSEQ + t0 + cc) = v;
  }
}

// ---------- 3: chunked flash attention v4 — K dbuf in LDS, V direct-to-reg,
// one barrier per tile. Block = (head, 32 q-rows, 384-key chunk).
__global__ __launch_bounds__(128) void k_attn(
    const u16* __restrict__ Qg, const u16* __restrict__ Kg,
    const u16* __restrict__ VTg, const int* __restrict__ segb,
    u16* __restrict__ Opart, float* __restrict__ Mp, float* __restrict__ Lp)
{
  __shared__ u16 Ks[2][64 * HD];   // 2 x 16KB, 256B rows, XOR-swizzled
  __shared__ u16 Ps[2][16 * 64];   // per-wave P, 128B rows, XOR-swizzled

  const int h  = blockIdx.x;
  const int qb = blockIdx.y;
  const int rc = blockIdx.z;
  const int q0 = qb * QBLK;

  const int c_lo = ((q0 - BM) > 0 ? (q0 - BM) : 0) / CHUNK;
  const int c_hi = (q0 + QBLK - 1) / CHUNK;
  if (rc > c_hi - c_lo) return;          // uniform early-exit (no loads)
  const int c = c_lo + rc;

  const int tid = threadIdx.x, lane = tid & 63, wv = tid >> 6;
  const int qw = q0 + wv * 16;
  const int r0 = (lane >> 4) * 4, c0 = lane & 15;
  const int koff = (lane >> 4) * 8;

  const int b = segb[0];                 // segment boundary (arithmetic mask)

  int loop_lo = q0 - BM; if (loop_lo < 0) loop_lo = 0;
  if (q0 >= b) loop_lo = (loop_lo > b) ? loop_lo : b;
  int s_lo = loop_lo & ~63;
  const int cs = c * CHUNK;
  if (s_lo < cs) s_lo = cs;
  int s_hi = q0 + QBLK;
  if (s_hi > cs + CHUNK) s_hi = cs + CHUNK;

  // Q fragments (scale pre-folded)
  s16x8 qf[4];
  {
    const u16* qp = Qg + ((size_t)h * TSEQ + qw + c0) * HD + koff;
    #pragma unroll
    for (int kk = 0; kk < 4; kk++) qf[kk] = *(const s16x8*)(qp + kk * 32);
  }

  int qt[4]; int qub[4];
  #pragma unroll
  for (int r = 0; r < 4; r++) { qt[r] = qw + r0 + r; qub[r] = (qt[r] >= b) ? 1 : 0; }

  f32x4 o[8];
  #pragma unroll
  for (int i = 0; i < 8; i++) o[i] = (f32x4){0.f, 0.f, 0.f, 0.f};
  float mrow[4] = {-1e30f, -1e30f, -1e30f, -1e30f};
  float lrow[4] = {0.f, 0.f, 0.f, 0.f};

  const u16* __restrict__ Vb = VTg + (size_t)h * HD * TSEQ;

  auto stageK = [&](int buf, int s0k) {
    #pragma unroll
    for (int i = 0; i < 8; i++) {
      const int L = tid * 16 + i * 2048;
      const int kr = L >> 8;
      const int kc = (L & 255) ^ ((kr & 7) << 4);
      gload_lds16(Kg + ((size_t)h * TSEQ + s0k + kr) * HD + (kc >> 1), (char*)Ks[buf] + L);
    }
  };

  if (s_lo < s_hi) {
    stageK(0, s_lo);
    int cur = 0;
    for (int s0 = s_lo; s0 < s_hi; s0 += 64) {
      SWAIT(0);                   // K(cur) landed (prefetched last iter / prologue)
      bar();                      // publish; Ks[cur^1] free to overwrite

      // S = Q K^T from Ks[cur]
      const char* kbase = (const char*)Ks[cur];
      f32x4 sv[4];
      #pragma unroll
      for (int n = 0; n < 4; n++) {
        sv[n] = (f32x4){0.f, 0.f, 0.f, 0.f};
        const int krow = n * 16 + c0;
        #pragma unroll
        for (int kk = 0; kk < 4; kk++) {
          const int kbyte = (krow << 8) + ((((kk * 32 + koff) << 1)) ^ ((krow & 7) << 4));
          const s16x8 kf = *(const s16x8*)(kbase + kbyte);
          sv[n] = __builtin_amdgcn_mfma_f32_16x16x32_bf16(qf[kk], kf, sv[n], 0, 0, 0);
        }
      }

      // V fragments direct from global (L2-resident; 64B-contiguous per (c0,kc))
      CFENCE();
      s16x8 vf[2][8];
      #pragma unroll
      for (int kc = 0; kc < 2; kc++)
        #pragma unroll
        for (int nf = 0; nf < 8; nf++)
          vf[kc][nf] = *(const s16x8*)(Vb + (size_t)(nf * 16 + c0) * TSEQ + s0 + kc * 32 + koff);
      CFENCE();

      // prefetch next K tile (issued AFTER V so counted wait keeps it in flight)
      const int sn = s0 + 64;
      if (sn < s_hi) stageK(cur ^ 1, sn);
      CFENCE();

      // arithmetic mask
      const bool keys_same_seg_as_q =
          ((s0 >= b) && (qw >= b)) || ((s0 + 63 < b) && (qw + 15 < b));
      const bool interior = (s0 + 64 <= qw) && (s0 >= qw + 15 - BM) && keys_same_seg_as_q;
      if (!interior) {
        #pragma unroll
        for (int n = 0; n < 4; n++) {
          const int key = s0 + n * 16 + c0;
          const int kub = (key >= b) ? 1 : 0;
          #pragma unroll
          for (int r = 0; r < 4; r++) {
            const bool ok = (key <= qt[r]) && (key >= qt[r] - BM) && (kub == qub[r]);
            sv[n][r] = ok ? sv[n][r] : -1e30f;
          }
        }
      }

      // tile row-max
      float pm[4];
      #pragma unroll
      for (int r = 0; r < 4; r++)
        pm[r] = fmaxf(fmaxf(sv[0][r], sv[1][r]), fmaxf(sv[2][r], sv[3][r]));
      #pragma unroll
      for (int m = 1; m < 16; m <<= 1)
        #pragma unroll
        for (int r = 0; r < 4; r++) pm[r] = fmaxf(pm[r], __shfl_xor(pm[r], m, 64));

      // defer-max rescale
      int need = 0;
      #pragma unroll
      for (int r = 0; r < 4; r++) need |= (pm[r] > mrow[r] + 8.f) ? 1 : 0;
      if (__any(need)) {
        #pragma unroll
        for (int r = 0; r < 4; r++) {
          const float mn = fmaxf(mrow[r], pm[r]);
          const float scl = __expf(mrow[r] - mn);
          mrow[r] = mn;
          lrow[r] *= scl;
          #pragma unroll
          for (int i = 0; i < 8; i++) o[i][r] *= scl;
        }
      }

      u16 pb[4][4];
      #pragma unroll
      for (int n = 0; n < 4; n++)
        #pragma unroll
        for (int r = 0; r < 4; r++) {
          const float p = (sv[n][r] < -0.5e30f) ? 0.f : __expf(sv[n][r] - mrow[r]);
          lrow[r] += p;
          pb[n][r] = f2b(p);
        }

      SWAIT(8);                   // V(16) drained; K(next)(<=8) stays in flight

      // P -> per-wave LDS (swizzled) -> PV A-fragments (within-wave)
      char* pbase = (char*)Ps[wv];
      #pragma unroll
      for (int n = 0; n < 4; n++)
        #pragma unroll
        for (int r = 0; r < 4; r++) {
          const int row = r0 + r;
          const int byt = (row << 7) + ((((n * 16 + c0) << 1)) ^ ((row & 7) << 4));
          *(u16*)(pbase + byt) = pb[n][r];
        }
      #pragma unroll
      for (int kc = 0; kc < 2; kc++) {
        const int pbyte = (c0 << 7) + ((((kc * 32 + koff) << 1)) ^ ((c0 & 7) << 4));
        const s16x8 pf = *(const s16x8*)(pbase + pbyte);
        #pragma unroll
        for (int nf = 0; nf < 8; nf++)
          o[nf] = __builtin_amdgcn_mfma_f32_16x16x32_bf16(pf, vf[kc][nf], o[nf], 0, 0, 0);
      }
      cur ^= 1;
    }
    SWAIT(0);                     // drain trailing prefetch
  }

  // final row-sum reduce (once per chunk)
  #pragma unroll
  for (int m = 1; m < 16; m <<= 1)
    #pragma unroll
    for (int r = 0; r < 4; r++) lrow[r] += __shfl_xor(lrow[r], m, 64);

  // write partials
  const int pidx = (h * NQB + qb) * NCMAX + rc;
  #pragma unroll
  for (int r = 0; r < 4; r++) {
    const int wrow = wv * 16 + r0 + r;
    u16* op = Opart + (size_t)pidx * (32 * 128) + wrow * 128;
    #pragma unroll
    for (int nf = 0; nf < 8; nf++) op[nf * 16 + c0] = f2b(o[nf][r]);
    if (c0 == 0) {
      Mp[pidx * 32 + wrow] = mrow[r];
      Lp[pidx * 32 + wrow] = lrow[r];
    }
  }
}

// ---------- 3b: merge partials, apply gate, write Y bf16 ----------
__global__ __launch_bounds__(256) void k_merge(
    const u16* __restrict__ Opart, const float* __restrict__ Mp,
    const float* __restrict__ Lp, const float* __restrict__ gateA,
    u16* __restrict__ Y)
{
  const int qb = blockIdx.x, h = blockIdx.y;
  const int q0 = qb * QBLK;
  const int c_lo = ((q0 - BM) > 0 ? (q0 - BM) : 0) / CHUNK;
  const int c_hi = (q0 + QBLK - 1) / CHUNK;
  const int nc = c_hi - c_lo + 1;

  const int tid = threadIdx.x;
  const int row = tid >> 3;
  const int dg = (tid & 7) * 16;
  const int qt = q0 + row;
  const int base = (h * NQB + qb) * NCMAX;

  float m = -1e30f;
  for (int rc = 0; rc < nc; rc++) {
    const float mc = Mp[(base + rc) * 32 + row];
    m = fmaxf(m, mc);
  }
  float l = 0.f;
  float acc[16];
  #pragma unroll
  for (int j = 0; j < 16; j++) acc[j] = 0.f;
  for (int rc = 0; rc < nc; rc++) {
    const float mc = Mp[(base + rc) * 32 + row];
    const float w = __expf(mc - m);
    l += w * Lp[(base + rc) * 32 + row];
    const u16* op = Opart + (size_t)(base + rc) * (32 * 128) + row * 128 + dg;
    const s16x8 v0 = *(const s16x8*)(op);
    const s16x8 v1 = *(const s16x8*)(op + 8);
    #pragma unroll
    for (int j = 0; j < 8; j++) {
      acc[j]     += w * b2f(((const u16*)&v0)[j]);
      acc[j + 8] += w * b2f(((const u16*)&v1)[j]);
    }
  }
  const float inv = (l > 0.f) ? (gateA[h * TSEQ + qt] / l) : 0.f;
  u16* yp = Y + (size_t)qt * DIMM + h * HD + dg;
  #pragma unroll
  for (int j = 0; j < 16; j++) yp[j] = f2b(acc[j] * inv);
}

// ---------- launch ----------
extern "C" void kernel_launch(void* const* d_in, const int* in_sizes, int n_in,
                              void* d_out, int out_size, void* d_ws, size_t ws_size,
                              hipStream_t stream) {
  const float* x    = (const float*)d_in[0];
  const float* qkvo = (const float*)d_in[1];
  const float* lam  = (const float*)d_in[2];
  const float* ve   = (const float*)d_in[3];
  const float* gwa  = (const float*)d_in[4];
  const float* gwv  = (const float*)d_in[5];
  const float* cosb = (const float*)d_in[6];
  const float* sinb = (const float*)d_in[7];
  const int*   seg  = (const int*)d_in[8];
  float* out = (float*)d_out;

  char* ws = (char*)d_ws;
  size_t off = 0;
  auto alloc = [&](size_t bytes) -> void* {
    void* p = ws + off;
    off += (bytes + 255) & ~(size_t)255;
    return p;
  };
  u16*   xb    = (u16*)alloc((size_t)TSEQ * DIMM * 2);
  u16*   wb    = (u16*)alloc((size_t)4 * DIMM * DIMM * 2);
  float* qkv   = (float*)alloc((size_t)TSEQ * 3 * DIMM * 4);   // dead after k_prep
  u16*   Qg    = (u16*)alloc((size_t)NH * TSEQ * HD * 2);
  u16*   Kg    = (u16*)alloc((size_t)NH * TSEQ * HD * 2);
  u16*   VTg   = (u16*)alloc((size_t)NH * HD * TSEQ * 2);
  float* gateA = (float*)alloc((size_t)NH * TSEQ * 4);
  u16*   Yg    = (u16*)alloc((size_t)TSEQ * DIMM * 2);
  int*   segb  = (int*)alloc(256);

  // partials aliased into the dead qkv buffer
  u16*   Opart = (u16*)qkv;
  float* Mp    = (float*)((char*)qkv + (size_t)NH * NQB * NCMAX * 32 * 128 * 2);
  float* Lp    = Mp + (size_t)NH * NQB * NCMAX * 32;

  k_convert<<<2048, 256, 0, stream>>>(x, qkvo, lam, xb, wb);
  k_gemm_nt<<<dim3(24, 24), 256, 0, stream>>>(xb, wb, qkv, TSEQ, 3 * DIMM, DIMM);
  k_prep<<<dim3(TSEQ / 32, NH), 256, 0, stream>>>(qkv, x, ve, cosb, sinb, gwa, gwv, seg,
                                                  Qg, Kg, VTg, gateA, segb);
  k_attn<<<dim3(NH, NQB, NCMAX), 128, 0, stream>>>(Qg, Kg, VTg, segb, Opart, Mp, Lp);
  k_merge<<<dim3(NQB, NH), 256, 0, stream>>>(Opart, Mp, Lp, gateA, Yg);
  k_gemm_nt<<<dim3(DIMM / 128, 24), 256, 0, stream>>>(Yg, wb + (size_t)3 * DIMM * DIMM, out, TSEQ, DIMM, DIMM);
}

// Round 10
// 206.481 us; speedup vs baseline: 1.1195x; 1.1195x over previous
//
#include <hip/hip_runtime.h>
#include <hip/hip_bf16.h>
#include <stdint.h>

#define TSEQ 3072
#define DIMM 1024
#define NH   8
#define HD   128
#define QBLK 64
#define BM   1408
#define CHUNK 384
#define NQB  (TSEQ / QBLK)   // 48
#define NCMAX 5

typedef float f32x4 __attribute__((ext_vector_type(4)));
typedef short s16x8 __attribute__((ext_vector_type(8)));
typedef unsigned short u16;

// ---------- helpers ----------
static __device__ __forceinline__ u16 f2b(float f) {
  union { float f; unsigned u; } a; a.f = f;
  unsigned r = a.u + 0x7FFFu + ((a.u >> 16) & 1u);   // RNE
  return (u16)(r >> 16);
}
static __device__ __forceinline__ float b2f(u16 u) {
  union { unsigned u; float f; } a; a.u = ((unsigned)u) << 16;
  return a.f;
}
static __device__ __forceinline__ void gload_lds16(const void* g, void* l) {
  __builtin_amdgcn_global_load_lds(
      (const __attribute__((address_space(1))) unsigned int*)(unsigned long long)g,
      (__attribute__((address_space(3))) unsigned int*)(unsigned long long)l,
      16, 0, 0);
}
static __device__ __forceinline__ void bar() {
  asm volatile("" ::: "memory");
  __builtin_amdgcn_s_barrier();
  asm volatile("" ::: "memory");
}
#define SWAIT(n) asm volatile("s_waitcnt vmcnt(" #n ")" ::: "memory")

// ---------- 0: f32 -> bf16 conversion (w scaled by sa_lambdas) ----------
__global__ __launch_bounds__(256) void k_convert(
    const float* __restrict__ x, const float* __restrict__ w,
    const float* __restrict__ lam,
    u16* __restrict__ xb, u16* __restrict__ wb)
{
  const int NX = TSEQ * DIMM;
  const int NW = 4 * DIMM * DIMM;
  const float l0 = lam[0], l1 = lam[1];
  const int n4 = (NX + NW) >> 2;
  for (int j = blockIdx.x * 256 + threadIdx.x; j < n4; j += gridDim.x * 256) {
    const int e = j << 2;
    float4 v; u16* dst; float s;
    if (e < NX) { v = *(const float4*)(x + e); dst = xb + e; s = 1.f; }
    else {
      const int we = e - NX;
      v = *(const float4*)(w + we);
      dst = wb + we;
      s = (we < 3 * DIMM * DIMM) ? l0 : l1;
    }
    dst[0] = f2b(v.x * s); dst[1] = f2b(v.y * s);
    dst[2] = f2b(v.z * s); dst[3] = f2b(v.w * s);
  }
}

// ---------- NT GEMM: C[M][N] = A[M][K] * B[N][K]^T  (bf16 in, f32 out) ----------
// double-buffered prefetch + XOR-swizzled LDS (proven round 7).
__global__ __launch_bounds__(256) void k_gemm_nt(
    const u16* __restrict__ A, const u16* __restrict__ B,
    float* __restrict__ C, int M, int N, int K)
{
  __shared__ u16 As[2][128 * 64];
  __shared__ u16 Bs[2][128 * 64];
  const int tid = threadIdx.x;
  const int lane = tid & 63, wv = tid >> 6;
  const int m0 = blockIdx.y * 128, n0 = blockIdx.x * 128;
  const int wm = (wv >> 1) * 64, wn = (wv & 1) * 64;
  const int c0 = lane & 15, r0 = (lane >> 4) * 4, koff = (lane >> 4) * 8;

  f32x4 acc[4][4];
  #pragma unroll
  for (int i = 0; i < 4; i++)
    #pragma unroll
    for (int j = 0; j < 4; j++) acc[i][j] = (f32x4){0.f, 0.f, 0.f, 0.f};

  const int srow  = tid >> 3;        // 0..31 (+ i*32)
  const int scolb = (tid & 7) * 16;  // byte offset within 128B row

  auto stage = [&](int buf, int kt) {
    #pragma unroll
    for (int i = 0; i < 4; i++) {
      const int row = srow + i * 32;
      const int scb = scolb ^ ((row & 7) << 4);   // inverse-swizzled source col (bytes)
      const int ldst = row * 128 + scolb;         // linear LDS dest
      gload_lds16(A + (size_t)(m0 + row) * K + kt + (scb >> 1), (char*)As[buf] + ldst);
      gload_lds16(B + (size_t)(n0 + row) * K + kt + (scb >> 1), (char*)Bs[buf] + ldst);
    }
  };

  stage(0, 0);
  int cur = 0;
  for (int kt = 0; kt < K; kt += 64) {
    if (kt + 64 < K) {
      stage(cur ^ 1, kt + 64);
      SWAIT(8);
    } else {
      SWAIT(0);
    }
    bar();

    #pragma unroll
    for (int kk = 0; kk < 2; kk++) {
      s16x8 af[4], bf[4];
      #pragma unroll
      for (int i = 0; i < 4; i++) {
        const int ar = wm + i * 16 + c0;
        const int br = wn + i * 16 + c0;
        const int cb = (kk * 32 + koff) * 2;
        af[i] = *(const s16x8*)((const char*)As[cur] + ar * 128 + (cb ^ ((ar & 7) << 4)));
        bf[i] = *(const s16x8*)((const char*)Bs[cur] + br * 128 + (cb ^ ((br & 7) << 4)));
      }
      #pragma unroll
      for (int i = 0; i < 4; i++)
        #pragma unroll
        for (int j = 0; j < 4; j++)
          acc[i][j] = __builtin_amdgcn_mfma_f32_16x16x32_bf16(af[i], bf[j], acc[i][j], 0, 0, 0);
    }

    bar();
    cur ^= 1;
  }

  #pragma unroll
  for (int i = 0; i < 4; i++)
    #pragma unroll
    for (int j = 0; j < 4; j++) {
      float* cp = C + (size_t)(m0 + wm + i * 16 + r0) * N + n0 + wn + j * 16 + c0;
      #pragma unroll
      for (int r = 0; r < 4; r++) cp[(size_t)r * N] = acc[i][j][r];
    }
}

// ---------- 2: fused prep v3. Block: 256 thr (4 waves), owns (h, 32 t-rows) ----------
__global__ __launch_bounds__(256) void k_prep(
    const float* __restrict__ qkv, const float* __restrict__ x,
    const float* __restrict__ ve, const float* __restrict__ cosb,
    const float* __restrict__ sinb, const float* __restrict__ gwa,
    const float* __restrict__ gwv, const int* __restrict__ seg,
    u16* __restrict__ Qg, u16* __restrict__ Kg, u16* __restrict__ VTg,
    float* __restrict__ gateA, int* __restrict__ segb)
{
  __shared__ u16 vtile[32][130];   // [t][d], padded stride
  const int tid = threadIdx.x;
  const int lane = tid & 63, w = tid >> 6;
  const int h = blockIdx.y;
  const int t0 = blockIdx.x * 32;

  if (h == 0 && t0 == 0 && tid == 0) {
    const int sv = seg[0];
    int lo = 1, hi = TSEQ;
    while (lo < hi) { const int mid = (lo + hi) >> 1; if (seg[mid] == sv) lo = mid + 1; else hi = mid; }
    segb[0] = lo;
  }

  #pragma unroll
  for (int it = 0; it < 8; ++it) {
    const int tt = it * 4 + w;
    const int t = t0 + tt;
    const int tp = (t == 0) ? 0 : t - 1;

    const float* qrow = qkv + (size_t)t * (3 * DIMM) + h * HD;
    const float* krow = qrow + DIMM;
    const float* vrow = qrow + 2 * DIMM;
    const float* prow = qkv + (size_t)tp * (3 * DIMM) + DIMM + h * HD;

    float q1 = qrow[lane], q2 = qrow[lane + 64];
    float k1 = krow[lane], k2 = krow[lane + 64];
    float p1 = prow[lane], p2 = prow[lane + 64];

    float sq = q1 * q1 + q2 * q2, sk = k1 * k1 + k2 * k2, sp = p1 * p1 + p2 * p2;
    #pragma unroll
    for (int m = 1; m < 64; m <<= 1) {
      sq += __shfl_xor(sq, m, 64);
      sk += __shfl_xor(sk, m, 64);
      sp += __shfl_xor(sp, m, 64);
    }
    const float rq = rsqrtf(sq * (1.f / 128.f) + 1e-6f);
    const float rk = rsqrtf(sk * (1.f / 128.f) + 1e-6f);
    const float rp = rsqrtf(sp * (1.f / 128.f) + 1e-6f);
    q1 *= rq; q2 *= rq; k1 *= rk; k2 *= rk; p1 *= rp; p2 *= rp;

    const float c  = cosb[t * 64 + lane],  s  = sinb[t * 64 + lane];
    const float cp = cosb[tp * 64 + lane], spv = sinb[tp * 64 + lane];
    const float qo1 =  q1 * c + q2 * s,   qo2 = -q1 * s + q2 * c;
    const float ko1 =  k1 * c + k2 * s,   ko2 = -k1 * s + k2 * c;
    const float po1 =  p1 * cp + p2 * spv, po2 = -p1 * spv + p2 * cp;
    const float m1 = (lane < 32) ? ko1 : po1;
    const float m2 = (lane < 32) ? ko2 : po2;

    const size_t qkbase = ((size_t)h * TSEQ + t) * HD + lane;
    Qg[qkbase] = f2b(qo1 * 0.1f); Qg[qkbase + 64] = f2b(qo2 * 0.1f);  // attn scale folded
    Kg[qkbase] = f2b(m1);  Kg[qkbase + 64] = f2b(m2);

    float dv = 0.f, da = 0.f;
    #pragma unroll
    for (int g = 0; g < 16; g++) {
      const float xv = x[(size_t)t * DIMM + g];
      dv += xv * gwv[h * 16 + g];
      da += xv * gwa[h * 16 + g];
    }
    const float vg = 2.f / (1.f + __expf(-dv));
    const float v1 = vrow[lane]      + vg * ve[(size_t)t * DIMM + h * HD + lane];
    const float v2 = vrow[lane + 64] + vg * ve[(size_t)t * DIMM + h * HD + lane + 64];
    vtile[tt][lane] = f2b(v1); vtile[tt][lane + 64] = f2b(v2);
    if (lane == 0) gateA[h * TSEQ + t] = 1.f / (1.f + __expf(-da));
  }
  __syncthreads();
  // transpose write-out: VT[h][d][t0..t0+31], 64B chunks per d-row
  #pragma unroll
  for (int rep = 0; rep < 2; ++rep) {
    const int d = rep * 64 + (tid >> 2);
    const int cc = (tid & 3) * 8;
    s16x8 v;
    #pragma unroll
    for (int j = 0; j < 8; j++) ((u16*)&v)[j] = vtile[cc + j][d];
    *(s16x8*)(VTg + ((size_t)h * HD + d) * TSEQ + t0 + cc) = v;
  }
}

// ---------- 3: chunked flash attention (round-7 inner loop, QBLK=64, 4 waves) ----------
// Block = (head, 64 q-rows, 384-key chunk). grid (NH, NQB, NCMAX); head fastest.
// Each staged K/V tile feeds 4 waves (2x arithmetic intensity vs QBLK=32).
__global__ __launch_bounds__(256) void k_attn(
    const u16* __restrict__ Qg, const u16* __restrict__ Kg,
    const u16* __restrict__ VTg, const int* __restrict__ segb,
    u16* __restrict__ Opart, float* __restrict__ Mp, float* __restrict__ Lp)
{
  __shared__ u16 Ks[2][64 * HD];   // 2 x 16KB, 256B rows, XOR-swizzled
  __shared__ u16 Vs[HD * 64];      // 16KB, 128B rows, XOR-swizzled
  __shared__ u16 Ps[4][16 * 64];   // per-wave P, 128B rows, XOR-swizzled

  const int h  = blockIdx.x;
  const int qb = blockIdx.y;
  const int rc = blockIdx.z;
  const int q0 = qb * QBLK;

  const int c_lo = ((q0 - BM) > 0 ? (q0 - BM) : 0) / CHUNK;
  const int c_hi = (q0 + QBLK - 1) / CHUNK;
  if (rc > c_hi - c_lo) return;          // uniform early-exit (no loads)
  const int c = c_lo + rc;

  const int tid = threadIdx.x, lane = tid & 63, wv = tid >> 6;
  const int qw = q0 + wv * 16;
  const int r0 = (lane >> 4) * 4, c0 = lane & 15;
  const int koff = (lane >> 4) * 8;

  const int b = segb[0];                 // segment boundary (arithmetic mask)

  int loop_lo = q0 - BM; if (loop_lo < 0) loop_lo = 0;
  if (q0 >= b) loop_lo = (loop_lo > b) ? loop_lo : b;
  int s_lo = loop_lo & ~63;
  const int cs = c * CHUNK;
  if (s_lo < cs) s_lo = cs;
  int s_hi = q0 + QBLK;
  if (s_hi > cs + CHUNK) s_hi = cs + CHUNK;

  // Q fragments (scale pre-folded)
  s16x8 qf[4];
  {
    const u16* qp = Qg + ((size_t)h * TSEQ + qw + c0) * HD + koff;
    #pragma unroll
    for (int kk = 0; kk < 4; kk++) qf[kk] = *(const s16x8*)(qp + kk * 32);
  }

  int qt[4]; int qub[4];
  #pragma unroll
  for (int r = 0; r < 4; r++) { qt[r] = qw + r0 + r; qub[r] = (qt[r] >= b) ? 1 : 0; }

  f32x4 o[8];
  #pragma unroll
  for (int i = 0; i < 8; i++) o[i] = (f32x4){0.f, 0.f, 0.f, 0.f};
  float mrow[4] = {-1e30f, -1e30f, -1e30f, -1e30f};
  float lrow[4] = {0.f, 0.f, 0.f, 0.f};   // per-lane partials, reduced once at end

  auto stageK = [&](int buf, int s0k) {
    #pragma unroll
    for (int i = 0; i < 4; i++) {
      const int L = tid * 16 + i * 4096;
      const int kr = L >> 8;
      const int kc = (L & 255) ^ ((kr & 7) << 4);
      gload_lds16(Kg + ((size_t)h * TSEQ + s0k + kr) * HD + (kc >> 1), (char*)Ks[buf] + L);
    }
  };
  auto stageV = [&](int s0v) {
    #pragma unroll
    for (int i = 0; i < 4; i++) {
      const int L = tid * 16 + i * 4096;
      const int vr = L >> 7;
      const int vc = (L & 127) ^ ((vr & 7) << 4);
      gload_lds16(VTg + ((size_t)h * HD + vr) * TSEQ + s0v + (vc >> 1), (char*)Vs + L);
    }
  };

  if (s_lo < s_hi) {
    stageK(0, s_lo);
    int cur = 0;
    for (int s0 = s_lo; s0 < s_hi; s0 += 64) {
      bar();                      // PV(prev) done -> Vs reusable
      stageV(s0);                 // 4 loads
      int sn = s0 + 64; if (sn >= s_hi) sn = s0;
      stageK(cur ^ 1, sn);        // 4 loads
      SWAIT(8);                   // K(s0) landed; V(s0)+K(next) in flight
      bar();

      const char* kbase = (const char*)Ks[cur];
      f32x4 sv[4];
      #pragma unroll
      for (int n = 0; n < 4; n++) {
        sv[n] = (f32x4){0.f, 0.f, 0.f, 0.f};
        const int krow = n * 16 + c0;
        #pragma unroll
        for (int kk = 0; kk < 4; kk++) {
          const int kbyte = (krow << 8) + ((((kk * 32 + koff) << 1)) ^ ((krow & 7) << 4));
          const s16x8 kf = *(const s16x8*)(kbase + kbyte);
          sv[n] = __builtin_amdgcn_mfma_f32_16x16x32_bf16(qf[kk], kf, sv[n], 0, 0, 0);
        }
      }

      // arithmetic mask (no seg[] loads)
      const bool keys_same_seg_as_q =
          ((s0 >= b) && (qw >= b)) || ((s0 + 63 < b) && (qw + 15 < b));
      const bool interior = (s0 + 64 <= qw) && (s0 >= qw + 15 - BM) && keys_same_seg_as_q;
      if (!interior) {
        #pragma unroll
        for (int n = 0; n < 4; n++) {
          const int key = s0 + n * 16 + c0;
          const int kub = (key >= b) ? 1 : 0;
          #pragma unroll
          for (int r = 0; r < 4; r++) {
            const bool ok = (key <= qt[r]) && (key >= qt[r] - BM) && (kub == qub[r]);
            sv[n][r] = ok ? sv[n][r] : -1e30f;
          }
        }
      }

      // tile row-max
      float pm[4];
      #pragma unroll
      for (int r = 0; r < 4; r++)
        pm[r] = fmaxf(fmaxf(sv[0][r], sv[1][r]), fmaxf(sv[2][r], sv[3][r]));
      #pragma unroll
      for (int m = 1; m < 16; m <<= 1)
        #pragma unroll
        for (int r = 0; r < 4; r++) pm[r] = fmaxf(pm[r], __shfl_xor(pm[r], m, 64));

      // defer-max rescale
      int need = 0;
      #pragma unroll
      for (int r = 0; r < 4; r++) need |= (pm[r] > mrow[r] + 8.f) ? 1 : 0;
      if (__any(need)) {
        #pragma unroll
        for (int r = 0; r < 4; r++) {
          const float mn = fmaxf(mrow[r], pm[r]);
          const float scl = __expf(mrow[r] - mn);
          mrow[r] = mn;
          lrow[r] *= scl;
          #pragma unroll
          for (int i = 0; i < 8; i++) o[i][r] *= scl;
        }
      }

      u16 pb[4][4];
      #pragma unroll
      for (int n = 0; n < 4; n++)
        #pragma unroll
        for (int r = 0; r < 4; r++) {
          const float p = (sv[n][r] < -0.5e30f) ? 0.f : __expf(sv[n][r] - mrow[r]);
          lrow[r] += p;
          pb[n][r] = f2b(p);
        }

      // P -> per-wave LDS (swizzled), re-fragment as PV A-operand
      char* pbase = (char*)Ps[wv];
      #pragma unroll
      for (int n = 0; n < 4; n++)
        #pragma unroll
        for (int r = 0; r < 4; r++) {
          const int row = r0 + r;
          const int byt = (row << 7) + ((((n * 16 + c0) << 1)) ^ ((row & 7) << 4));
          *(u16*)(pbase + byt) = pb[n][r];
        }

      SWAIT(4);                   // V(s0) landed; K(next) in flight
      bar();

      #pragma unroll
      for (int kc = 0; kc < 2; kc++) {
        const int pbyte = (c0 << 7) + ((((kc * 32 + koff) << 1)) ^ ((c0 & 7) << 4));
        const s16x8 pf = *(const s16x8*)(pbase + pbyte);
        #pragma unroll
        for (int nf = 0; nf < 8; nf++) {
          const int vrow = nf * 16 + c0;
          const int vbyte = (vrow << 7) + ((((kc * 32 + koff) << 1)) ^ ((vrow & 7) << 4));
          const s16x8 vf = *(const s16x8*)((const char*)Vs + vbyte);
          o[nf] = __builtin_amdgcn_mfma_f32_16x16x32_bf16(pf, vf, o[nf], 0, 0, 0);
        }
      }
      cur ^= 1;
    }
    SWAIT(0);                     // drain trailing prefetch
  }

  // final row-sum reduce (once per chunk)
  #pragma unroll
  for (int m = 1; m < 16; m <<= 1)
    #pragma unroll
    for (int r = 0; r < 4; r++) lrow[r] += __shfl_xor(lrow[r], m, 64);

  // write partials
  const int pidx = (h * NQB + qb) * NCMAX + rc;
  #pragma unroll
  for (int r = 0; r < 4; r++) {
    const int wrow = wv * 16 + r0 + r;
    u16* op = Opart + (size_t)pidx * (QBLK * 128) + wrow * 128;
    #pragma unroll
    for (int nf = 0; nf < 8; nf++) op[nf * 16 + c0] = f2b(o[nf][r]);
    if (c0 == 0) {
      Mp[pidx * QBLK + wrow] = mrow[r];
      Lp[pidx * QBLK + wrow] = lrow[r];
    }
  }
}

// ---------- 3b: merge partials, apply gate, write Y bf16 ----------
__global__ __launch_bounds__(256) void k_merge(
    const u16* __restrict__ Opart, const float* __restrict__ Mp,
    const float* __restrict__ Lp, const float* __restrict__ gateA,
    u16* __restrict__ Y)
{
  const int qb = blockIdx.x, h = blockIdx.y;
  const int q0 = qb * QBLK;
  const int c_lo = ((q0 - BM) > 0 ? (q0 - BM) : 0) / CHUNK;
  const int c_hi = (q0 + QBLK - 1) / CHUNK;
  const int nc = c_hi - c_lo + 1;

  const int tid = threadIdx.x;
  const int base = (h * NQB + qb) * NCMAX;

  #pragma unroll
  for (int rep = 0; rep < 2; ++rep) {
    const int row = rep * 32 + (tid >> 3);
    const int dg = (tid & 7) * 16;
    const int qt = q0 + row;

    float m = -1e30f;
    for (int rcx = 0; rcx < nc; rcx++) {
      const float mc = Mp[(base + rcx) * QBLK + row];
      m = fmaxf(m, mc);
    }
    float l = 0.f;
    float acc[16];
    #pragma unroll
    for (int j = 0; j < 16; j++) acc[j] = 0.f;
    for (int rcx = 0; rcx < nc; rcx++) {
      const float mc = Mp[(base + rcx) * QBLK + row];
      const float w = __expf(mc - m);
      l += w * Lp[(base + rcx) * QBLK + row];
      const u16* op = Opart + (size_t)(base + rcx) * (QBLK * 128) + row * 128 + dg;
      const s16x8 v0 = *(const s16x8*)(op);
      const s16x8 v1 = *(const s16x8*)(op + 8);
      #pragma unroll
      for (int j = 0; j < 8; j++) {
        acc[j]     += w * b2f(((const u16*)&v0)[j]);
        acc[j + 8] += w * b2f(((const u16*)&v1)[j]);
      }
    }
    const float inv = (l > 0.f) ? (gateA[h * TSEQ + qt] / l) : 0.f;
    u16* yp = Y + (size_t)qt * DIMM + h * HD + dg;
    #pragma unroll
    for (int j = 0; j < 16; j++) yp[j] = f2b(acc[j] * inv);
  }
}

// ---------- launch ----------
extern "C" void kernel_launch(void* const* d_in, const int* in_sizes, int n_in,
                              void* d_out, int out_size, void* d_ws, size_t ws_size,
                              hipStream_t stream) {
  const float* x    = (const float*)d_in[0];
  const float* qkvo = (const float*)d_in[1];
  const float* lam  = (const float*)d_in[2];
  const float* ve   = (const float*)d_in[3];
  const float* gwa  = (const float*)d_in[4];
  const float* gwv  = (const float*)d_in[5];
  const float* cosb = (const float*)d_in[6];
  const float* sinb = (const float*)d_in[7];
  const int*   seg  = (const int*)d_in[8];
  float* out = (float*)d_out;

  char* ws = (char*)d_ws;
  size_t off = 0;
  auto alloc = [&](size_t bytes) -> void* {
    void* p = ws + off;
    off += (bytes + 255) & ~(size_t)255;
    return p;
  };
  u16*   xb    = (u16*)alloc((size_t)TSEQ * DIMM * 2);
  u16*   wb    = (u16*)alloc((size_t)4 * DIMM * DIMM * 2);
  float* qkv   = (float*)alloc((size_t)TSEQ * 3 * DIMM * 4);   // dead after k_prep
  u16*   Qg    = (u16*)alloc((size_t)NH * TSEQ * HD * 2);
  u16*   Kg    = (u16*)alloc((size_t)NH * TSEQ * HD * 2);
  u16*   VTg   = (u16*)alloc((size_t)NH * HD * TSEQ * 2);
  float* gateA = (float*)alloc((size_t)NH * TSEQ * 4);
  u16*   Yg    = (u16*)alloc((size_t)TSEQ * DIMM * 2);
  int*   segb  = (int*)alloc(256);

  // partials aliased into the dead qkv buffer (30 MB + 0.5 + 0.5 <= 37.75 MB)
  u16*   Opart = (u16*)qkv;
  float* Mp    = (float*)((char*)qkv + (size_t)NH * NQB * NCMAX * QBLK * 128 * 2);
  float* Lp    = Mp + (size_t)NH * NQB * NCMAX * QBLK;

  k_convert<<<2048, 256, 0, stream>>>(x, qkvo, lam, xb, wb);
  k_gemm_nt<<<dim3(24, 24), 256, 0, stream>>>(xb, wb, qkv, TSEQ, 3 * DIMM, DIMM);
  k_prep<<<dim3(TSEQ / 32, NH), 256, 0, stream>>>(qkv, x, ve, cosb, sinb, gwa, gwv, seg,
                                                  Qg, Kg, VTg, gateA, segb);
  k_attn<<<dim3(NH, NQB, NCMAX), 256, 0, stream>>>(Qg, Kg, VTg, segb, Opart, Mp, Lp);
  k_merge<<<dim3(NQB, NH), 256, 0, stream>>>(Opart, Mp, Lp, gateA, Yg);
  k_gemm_nt<<<dim3(DIMM / 128, 24), 256, 0, stream>>>(Yg, wb + (size_t)3 * DIMM * DIMM, out, TSEQ, DIMM, DIMM);
}

// Round 11
// 198.540 us; speedup vs baseline: 1.1643x; 1.0400x over previous
//
#include <hip/hip_runtime.h>
#include <hip/hip_bf16.h>
#include <stdint.h>

#define TSEQ 3072
#define DIMM 1024
#define NH   8
#define HD   128
#define QBLK 64
#define BM   1408
#define CHUNK 384
#define NQB  (TSEQ / QBLK)   // 48
#define NCMAX 5

typedef float f32x4 __attribute__((ext_vector_type(4)));
typedef short s16x8 __attribute__((ext_vector_type(8)));
typedef unsigned short u16;

// ---------- helpers ----------
static __device__ __forceinline__ u16 f2b(float f) {
  union { float f; unsigned u; } a; a.f = f;
  unsigned r = a.u + 0x7FFFu + ((a.u >> 16) & 1u);   // RNE
  return (u16)(r >> 16);
}
static __device__ __forceinline__ float b2f(u16 u) {
  union { unsigned u; float f; } a; a.u = ((unsigned)u) << 16;
  return a.f;
}
static __device__ __forceinline__ void store_out(float* p, float v) { *p = v; }
static __device__ __forceinline__ void store_out(u16* p, float v) { *p = f2b(v); }
static __device__ __forceinline__ void gload_lds16(const void* g, void* l) {
  __builtin_amdgcn_global_load_lds(
      (const __attribute__((address_space(1))) unsigned int*)(unsigned long long)g,
      (__attribute__((address_space(3))) unsigned int*)(unsigned long long)l,
      16, 0, 0);
}
static __device__ __forceinline__ void bar() {
  asm volatile("" ::: "memory");
  __builtin_amdgcn_s_barrier();
  asm volatile("" ::: "memory");
}
#define SWAIT(n) asm volatile("s_waitcnt vmcnt(" #n ")" ::: "memory")

// ---------- 0: f32 -> bf16 conversion (w scaled by sa_lambdas) ----------
__global__ __launch_bounds__(256) void k_convert(
    const float* __restrict__ x, const float* __restrict__ w,
    const float* __restrict__ lam,
    u16* __restrict__ xb, u16* __restrict__ wb)
{
  const int NX = TSEQ * DIMM;
  const int NW = 4 * DIMM * DIMM;
  const float l0 = lam[0], l1 = lam[1];
  const int n4 = (NX + NW) >> 2;
  for (int j = blockIdx.x * 256 + threadIdx.x; j < n4; j += gridDim.x * 256) {
    const int e = j << 2;
    float4 v; u16* dst; float s;
    if (e < NX) { v = *(const float4*)(x + e); dst = xb + e; s = 1.f; }
    else {
      const int we = e - NX;
      v = *(const float4*)(w + we);
      dst = wb + we;
      s = (we < 3 * DIMM * DIMM) ? l0 : l1;
    }
    dst[0] = f2b(v.x * s); dst[1] = f2b(v.y * s);
    dst[2] = f2b(v.z * s); dst[3] = f2b(v.w * s);
  }
}

// ---------- NT GEMM: C[M][N] = A[M][K] * B[N][K]^T  (bf16 in, f32/bf16 out) ----------
// double-buffered prefetch + XOR-swizzled LDS (proven round 7).
template <typename TO>
__global__ __launch_bounds__(256) void k_gemm_nt(
    const u16* __restrict__ A, const u16* __restrict__ B,
    TO* __restrict__ C, int M, int N, int K)
{
  __shared__ u16 As[2][128 * 64];
  __shared__ u16 Bs[2][128 * 64];
  const int tid = threadIdx.x;
  const int lane = tid & 63, wv = tid >> 6;
  const int m0 = blockIdx.y * 128, n0 = blockIdx.x * 128;
  const int wm = (wv >> 1) * 64, wn = (wv & 1) * 64;
  const int c0 = lane & 15, r0 = (lane >> 4) * 4, koff = (lane >> 4) * 8;

  f32x4 acc[4][4];
  #pragma unroll
  for (int i = 0; i < 4; i++)
    #pragma unroll
    for (int j = 0; j < 4; j++) acc[i][j] = (f32x4){0.f, 0.f, 0.f, 0.f};

  const int srow  = tid >> 3;        // 0..31 (+ i*32)
  const int scolb = (tid & 7) * 16;  // byte offset within 128B row

  auto stage = [&](int buf, int kt) {
    #pragma unroll
    for (int i = 0; i < 4; i++) {
      const int row = srow + i * 32;
      const int scb = scolb ^ ((row & 7) << 4);   // inverse-swizzled source col (bytes)
      const int ldst = row * 128 + scolb;         // linear LDS dest
      gload_lds16(A + (size_t)(m0 + row) * K + kt + (scb >> 1), (char*)As[buf] + ldst);
      gload_lds16(B + (size_t)(n0 + row) * K + kt + (scb >> 1), (char*)Bs[buf] + ldst);
    }
  };

  stage(0, 0);
  int cur = 0;
  for (int kt = 0; kt < K; kt += 64) {
    if (kt + 64 < K) {
      stage(cur ^ 1, kt + 64);
      SWAIT(8);
    } else {
      SWAIT(0);
    }
    bar();

    #pragma unroll
    for (int kk = 0; kk < 2; kk++) {
      s16x8 af[4], bf[4];
      #pragma unroll
      for (int i = 0; i < 4; i++) {
        const int ar = wm + i * 16 + c0;
        const int br = wn + i * 16 + c0;
        const int cb = (kk * 32 + koff) * 2;
        af[i] = *(const s16x8*)((const char*)As[cur] + ar * 128 + (cb ^ ((ar & 7) << 4)));
        bf[i] = *(const s16x8*)((const char*)Bs[cur] + br * 128 + (cb ^ ((br & 7) << 4)));
      }
      #pragma unroll
      for (int i = 0; i < 4; i++)
        #pragma unroll
        for (int j = 0; j < 4; j++)
          acc[i][j] = __builtin_amdgcn_mfma_f32_16x16x32_bf16(af[i], bf[j], acc[i][j], 0, 0, 0);
    }

    bar();
    cur ^= 1;
  }

  #pragma unroll
  for (int i = 0; i < 4; i++)
    #pragma unroll
    for (int j = 0; j < 4; j++) {
      TO* cp = C + (size_t)(m0 + wm + i * 16 + r0) * N + n0 + wn + j * 16 + c0;
      #pragma unroll
      for (int r = 0; r < 4; r++) store_out(cp + (size_t)r * N, acc[i][j][r]);
    }
}

// ---------- 2: fused prep v3 (qkv now bf16). Block: 256 thr, owns (h, 32 t-rows) ----------
__global__ __launch_bounds__(256) void k_prep(
    const u16* __restrict__ qkv, const float* __restrict__ x,
    const float* __restrict__ ve, const float* __restrict__ cosb,
    const float* __restrict__ sinb, const float* __restrict__ gwa,
    const float* __restrict__ gwv, const int* __restrict__ seg,
    u16* __restrict__ Qg, u16* __restrict__ Kg, u16* __restrict__ VTg,
    float* __restrict__ gateA, int* __restrict__ segb)
{
  __shared__ u16 vtile[32][130];   // [t][d], padded stride
  const int tid = threadIdx.x;
  const int lane = tid & 63, w = tid >> 6;
  const int h = blockIdx.y;
  const int t0 = blockIdx.x * 32;

  if (h == 0 && t0 == 0 && tid == 0) {
    const int sv = seg[0];
    int lo = 1, hi = TSEQ;
    while (lo < hi) { const int mid = (lo + hi) >> 1; if (seg[mid] == sv) lo = mid + 1; else hi = mid; }
    segb[0] = lo;
  }

  #pragma unroll
  for (int it = 0; it < 8; ++it) {
    const int tt = it * 4 + w;
    const int t = t0 + tt;
    const int tp = (t == 0) ? 0 : t - 1;

    const u16* qrow = qkv + (size_t)t * (3 * DIMM) + h * HD;
    const u16* krow = qrow + DIMM;
    const u16* vrow = qrow + 2 * DIMM;
    const u16* prow = qkv + (size_t)tp * (3 * DIMM) + DIMM + h * HD;

    float q1 = b2f(qrow[lane]), q2 = b2f(qrow[lane + 64]);
    float k1 = b2f(krow[lane]), k2 = b2f(krow[lane + 64]);
    float p1 = b2f(prow[lane]), p2 = b2f(prow[lane + 64]);

    float sq = q1 * q1 + q2 * q2, sk = k1 * k1 + k2 * k2, sp = p1 * p1 + p2 * p2;
    #pragma unroll
    for (int m = 1; m < 64; m <<= 1) {
      sq += __shfl_xor(sq, m, 64);
      sk += __shfl_xor(sk, m, 64);
      sp += __shfl_xor(sp, m, 64);
    }
    const float rq = rsqrtf(sq * (1.f / 128.f) + 1e-6f);
    const float rk = rsqrtf(sk * (1.f / 128.f) + 1e-6f);
    const float rp = rsqrtf(sp * (1.f / 128.f) + 1e-6f);
    q1 *= rq; q2 *= rq; k1 *= rk; k2 *= rk; p1 *= rp; p2 *= rp;

    const float c  = cosb[t * 64 + lane],  s  = sinb[t * 64 + lane];
    const float cp = cosb[tp * 64 + lane], spv = sinb[tp * 64 + lane];
    const float qo1 =  q1 * c + q2 * s,   qo2 = -q1 * s + q2 * c;
    const float ko1 =  k1 * c + k2 * s,   ko2 = -k1 * s + k2 * c;
    const float po1 =  p1 * cp + p2 * spv, po2 = -p1 * spv + p2 * cp;
    const float m1 = (lane < 32) ? ko1 : po1;
    const float m2 = (lane < 32) ? ko2 : po2;

    const size_t qkbase = ((size_t)h * TSEQ + t) * HD + lane;
    Qg[qkbase] = f2b(qo1 * 0.1f); Qg[qkbase + 64] = f2b(qo2 * 0.1f);  // attn scale folded
    Kg[qkbase] = f2b(m1);  Kg[qkbase + 64] = f2b(m2);

    float dv = 0.f, da = 0.f;
    #pragma unroll
    for (int g = 0; g < 16; g++) {
      const float xv = x[(size_t)t * DIMM + g];
      dv += xv * gwv[h * 16 + g];
      da += xv * gwa[h * 16 + g];
    }
    const float vg = 2.f / (1.f + __expf(-dv));
    const float v1 = b2f(vrow[lane])      + vg * ve[(size_t)t * DIMM + h * HD + lane];
    const float v2 = b2f(vrow[lane + 64]) + vg * ve[(size_t)t * DIMM + h * HD + lane + 64];
    vtile[tt][lane] = f2b(v1); vtile[tt][lane + 64] = f2b(v2);
    if (lane == 0) gateA[h * TSEQ + t] = 1.f / (1.f + __expf(-da));
  }
  __syncthreads();
  // transpose write-out: VT[h][d][t0..t0+31], 64B chunks per d-row
  #pragma unroll
  for (int rep = 0; rep < 2; ++rep) {
    const int d = rep * 64 + (tid >> 2);
    const int cc = (tid & 3) * 8;
    s16x8 v;
    #pragma unroll
    for (int j = 0; j < 8; j++) ((u16*)&v)[j] = vtile[cc + j][d];
    *(s16x8*)(VTg + ((size_t)h * HD + d) * TSEQ + t0 + cc) = v;
  }
}

// ---------- 3: chunked flash attention (QBLK=64, 4 waves, K dbuf + V LDS, T5 setprio) ----------
__global__ __launch_bounds__(256) void k_attn(
    const u16* __restrict__ Qg, const u16* __restrict__ Kg,
    const u16* __restrict__ VTg, const int* __restrict__ segb,
    u16* __restrict__ Opart, float* __restrict__ Mp, float* __restrict__ Lp)
{
  __shared__ u16 Ks[2][64 * HD];   // 2 x 16KB, 256B rows, XOR-swizzled
  __shared__ u16 Vs[HD * 64];      // 16KB, 128B rows, XOR-swizzled
  __shared__ u16 Ps[4][16 * 64];   // per-wave P, 128B rows, XOR-swizzled

  const int h  = blockIdx.x;
  const int qb = blockIdx.y;
  const int rc = blockIdx.z;
  const int q0 = qb * QBLK;

  const int c_lo = ((q0 - BM) > 0 ? (q0 - BM) : 0) / CHUNK;
  const int c_hi = (q0 + QBLK - 1) / CHUNK;
  if (rc > c_hi - c_lo) return;          // uniform early-exit (no loads)
  const int c = c_lo + rc;

  const int tid = threadIdx.x, lane = tid & 63, wv = tid >> 6;
  const int qw = q0 + wv * 16;
  const int r0 = (lane >> 4) * 4, c0 = lane & 15;
  const int koff = (lane >> 4) * 8;

  const int b = segb[0];                 // segment boundary (arithmetic mask)

  int loop_lo = q0 - BM; if (loop_lo < 0) loop_lo = 0;
  if (q0 >= b) loop_lo = (loop_lo > b) ? loop_lo : b;
  int s_lo = loop_lo & ~63;
  const int cs = c * CHUNK;
  if (s_lo < cs) s_lo = cs;
  int s_hi = q0 + QBLK;
  if (s_hi > cs + CHUNK) s_hi = cs + CHUNK;

  // Q fragments (scale pre-folded)
  s16x8 qf[4];
  {
    const u16* qp = Qg + ((size_t)h * TSEQ + qw + c0) * HD + koff;
    #pragma unroll
    for (int kk = 0; kk < 4; kk++) qf[kk] = *(const s16x8*)(qp + kk * 32);
  }

  int qt[4]; int qub[4];
  #pragma unroll
  for (int r = 0; r < 4; r++) { qt[r] = qw + r0 + r; qub[r] = (qt[r] >= b) ? 1 : 0; }

  f32x4 o[8];
  #pragma unroll
  for (int i = 0; i < 8; i++) o[i] = (f32x4){0.f, 0.f, 0.f, 0.f};
  float mrow[4] = {-1e30f, -1e30f, -1e30f, -1e30f};
  float lrow[4] = {0.f, 0.f, 0.f, 0.f};   // per-lane partials, reduced once at end

  auto stageK = [&](int buf, int s0k) {
    #pragma unroll
    for (int i = 0; i < 4; i++) {
      const int L = tid * 16 + i * 4096;
      const int kr = L >> 8;
      const int kc = (L & 255) ^ ((kr & 7) << 4);
      gload_lds16(Kg + ((size_t)h * TSEQ + s0k + kr) * HD + (kc >> 1), (char*)Ks[buf] + L);
    }
  };
  auto stageV = [&](int s0v) {
    #pragma unroll
    for (int i = 0; i < 4; i++) {
      const int L = tid * 16 + i * 4096;
      const int vr = L >> 7;
      const int vc = (L & 127) ^ ((vr & 7) << 4);
      gload_lds16(VTg + ((size_t)h * HD + vr) * TSEQ + s0v + (vc >> 1), (char*)Vs + L);
    }
  };

  if (s_lo < s_hi) {
    stageK(0, s_lo);
    int cur = 0;
    for (int s0 = s_lo; s0 < s_hi; s0 += 64) {
      bar();                      // PV(prev) done -> Vs reusable
      stageV(s0);                 // 4 loads
      int sn = s0 + 64; if (sn >= s_hi) sn = s0;
      stageK(cur ^ 1, sn);        // 4 loads
      SWAIT(8);                   // K(s0) landed; V(s0)+K(next) in flight
      bar();

      const char* kbase = (const char*)Ks[cur];
      f32x4 sv[4];
      __builtin_amdgcn_s_setprio(1);
      #pragma unroll
      for (int n = 0; n < 4; n++) {
        sv[n] = (f32x4){0.f, 0.f, 0.f, 0.f};
        const int krow = n * 16 + c0;
        #pragma unroll
        for (int kk = 0; kk < 4; kk++) {
          const int kbyte = (krow << 8) + ((((kk * 32 + koff) << 1)) ^ ((krow & 7) << 4));
          const s16x8 kf = *(const s16x8*)(kbase + kbyte);
          sv[n] = __builtin_amdgcn_mfma_f32_16x16x32_bf16(qf[kk], kf, sv[n], 0, 0, 0);
        }
      }
      __builtin_amdgcn_s_setprio(0);

      // arithmetic mask (no seg[] loads)
      const bool keys_same_seg_as_q =
          ((s0 >= b) && (qw >= b)) || ((s0 + 63 < b) && (qw + 15 < b));
      const bool interior = (s0 + 64 <= qw) && (s0 >= qw + 15 - BM) && keys_same_seg_as_q;
      if (!interior) {
        #pragma unroll
        for (int n = 0; n < 4; n++) {
          const int key = s0 + n * 16 + c0;
          const int kub = (key >= b) ? 1 : 0;
          #pragma unroll
          for (int r = 0; r < 4; r++) {
            const bool ok = (key <= qt[r]) && (key >= qt[r] - BM) && (kub == qub[r]);
            sv[n][r] = ok ? sv[n][r] : -1e30f;
          }
        }
      }

      // tile row-max
      float pm[4];
      #pragma unroll
      for (int r = 0; r < 4; r++)
        pm[r] = fmaxf(fmaxf(sv[0][r], sv[1][r]), fmaxf(sv[2][r], sv[3][r]));
      #pragma unroll
      for (int m = 1; m < 16; m <<= 1)
        #pragma unroll
        for (int r = 0; r < 4; r++) pm[r] = fmaxf(pm[r], __shfl_xor(pm[r], m, 64));

      // defer-max rescale
      int need = 0;
      #pragma unroll
      for (int r = 0; r < 4; r++) need |= (pm[r] > mrow[r] + 8.f) ? 1 : 0;
      if (__any(need)) {
        #pragma unroll
        for (int r = 0; r < 4; r++) {
          const float mn = fmaxf(mrow[r], pm[r]);
          const float scl = __expf(mrow[r] - mn);
          mrow[r] = mn;
          lrow[r] *= scl;
          #pragma unroll
          for (int i = 0; i < 8; i++) o[i][r] *= scl;
        }
      }

      u16 pb[4][4];
      #pragma unroll
      for (int n = 0; n < 4; n++)
        #pragma unroll
        for (int r = 0; r < 4; r++) {
          const float p = (sv[n][r] < -0.5e30f) ? 0.f : __expf(sv[n][r] - mrow[r]);
          lrow[r] += p;
          pb[n][r] = f2b(p);
        }

      // P -> per-wave LDS (swizzled), re-fragment as PV A-operand
      char* pbase = (char*)Ps[wv];
      #pragma unroll
      for (int n = 0; n < 4; n++)
        #pragma unroll
        for (int r = 0; r < 4; r++) {
          const int row = r0 + r;
          const int byt = (row << 7) + ((((n * 16 + c0) << 1)) ^ ((row & 7) << 4));
          *(u16*)(pbase + byt) = pb[n][r];
        }

      SWAIT(4);                   // V(s0) landed; K(next) in flight
      bar();

      __builtin_amdgcn_s_setprio(1);
      #pragma unroll
      for (int kc = 0; kc < 2; kc++) {
        const int pbyte = (c0 << 7) + ((((kc * 32 + koff) << 1)) ^ ((c0 & 7) << 4));
        const s16x8 pf = *(const s16x8*)(pbase + pbyte);
        #pragma unroll
        for (int nf = 0; nf < 8; nf++) {
          const int vrow = nf * 16 + c0;
          const int vbyte = (vrow << 7) + ((((kc * 32 + koff) << 1)) ^ ((vrow & 7) << 4));
          const s16x8 vf = *(const s16x8*)((const char*)Vs + vbyte);
          o[nf] = __builtin_amdgcn_mfma_f32_16x16x32_bf16(pf, vf, o[nf], 0, 0, 0);
        }
      }
      __builtin_amdgcn_s_setprio(0);
      cur ^= 1;
    }
    SWAIT(0);                     // drain trailing prefetch
  }

  // final row-sum reduce (once per chunk)
  #pragma unroll
  for (int m = 1; m < 16; m <<= 1)
    #pragma unroll
    for (int r = 0; r < 4; r++) lrow[r] += __shfl_xor(lrow[r], m, 64);

  // write partials
  const int pidx = (h * NQB + qb) * NCMAX + rc;
  #pragma unroll
  for (int r = 0; r < 4; r++) {
    const int wrow = wv * 16 + r0 + r;
    u16* op = Opart + (size_t)pidx * (QBLK * 128) + wrow * 128;
    #pragma unroll
    for (int nf = 0; nf < 8; nf++) op[nf * 16 + c0] = f2b(o[nf][r]);
    if (c0 == 0) {
      Mp[pidx * QBLK + wrow] = mrow[r];
      Lp[pidx * QBLK + wrow] = lrow[r];
    }
  }
}

// ---------- 3b: merge partials, apply gate, write Y bf16 ----------
__global__ __launch_bounds__(256) void k_merge(
    const u16* __restrict__ Opart, const float* __restrict__ Mp,
    const float* __restrict__ Lp, const float* __restrict__ gateA,
    u16* __restrict__ Y)
{
  const int qb = blockIdx.x, h = blockIdx.y;
  const int q0 = qb * QBLK;
  const int c_lo = ((q0 - BM) > 0 ? (q0 - BM) : 0) / CHUNK;
  const int c_hi = (q0 + QBLK - 1) / CHUNK;
  const int nc = c_hi - c_lo + 1;

  const int tid = threadIdx.x;
  const int base = (h * NQB + qb) * NCMAX;

  #pragma unroll
  for (int rep = 0; rep < 2; ++rep) {
    const int row = rep * 32 + (tid >> 3);
    const int dg = (tid & 7) * 16;
    const int qt = q0 + row;

    float m = -1e30f;
    for (int rcx = 0; rcx < nc; rcx++) {
      const float mc = Mp[(base + rcx) * QBLK + row];
      m = fmaxf(m, mc);
    }
    float l = 0.f;
    float acc[16];
    #pragma unroll
    for (int j = 0; j < 16; j++) acc[j] = 0.f;
    for (int rcx = 0; rcx < nc; rcx++) {
      const float mc = Mp[(base + rcx) * QBLK + row];
      const float w = __expf(mc - m);
      l += w * Lp[(base + rcx) * QBLK + row];
      const u16* op = Opart + (size_t)(base + rcx) * (QBLK * 128) + row * 128 + dg;
      const s16x8 v0 = *(const s16x8*)(op);
      const s16x8 v1 = *(const s16x8*)(op + 8);
      #pragma unroll
      for (int j = 0; j < 8; j++) {
        acc[j]     += w * b2f(((const u16*)&v0)[j]);
        acc[j + 8] += w * b2f(((const u16*)&v1)[j]);
      }
    }
    const float inv = (l > 0.f) ? (gateA[h * TSEQ + qt] / l) : 0.f;
    u16* yp = Y + (size_t)qt * DIMM + h * HD + dg;
    #pragma unroll
    for (int j = 0; j < 16; j++) yp[j] = f2b(acc[j] * inv);
  }
}

// ---------- launch ----------
extern "C" void kernel_launch(void* const* d_in, const int* in_sizes, int n_in,
                              void* d_out, int out_size, void* d_ws, size_t ws_size,
                              hipStream_t stream) {
  const float* x    = (const float*)d_in[0];
  const float* qkvo = (const float*)d_in[1];
  const float* lam  = (const float*)d_in[2];
  const float* ve   = (const float*)d_in[3];
  const float* gwa  = (const float*)d_in[4];
  const float* gwv  = (const float*)d_in[5];
  const float* cosb = (const float*)d_in[6];
  const float* sinb = (const float*)d_in[7];
  const int*   seg  = (const int*)d_in[8];
  float* out = (float*)d_out;

  char* ws = (char*)d_ws;
  size_t off = 0;
  auto alloc = [&](size_t bytes) -> void* {
    void* p = ws + off;
    off += (bytes + 255) & ~(size_t)255;
    return p;
  };
  u16*   xb    = (u16*)alloc((size_t)TSEQ * DIMM * 2);
  u16*   wb    = (u16*)alloc((size_t)4 * DIMM * DIMM * 2);
  u16*   qkv   = (u16*)alloc((size_t)TSEQ * 3 * DIMM * 2);     // bf16 now (half traffic)
  u16*   Qg    = (u16*)alloc((size_t)NH * TSEQ * HD * 2);
  u16*   Kg    = (u16*)alloc((size_t)NH * TSEQ * HD * 2);
  u16*   VTg   = (u16*)alloc((size_t)NH * HD * TSEQ * 2);
  float* gateA = (float*)alloc((size_t)NH * TSEQ * 4);
  u16*   Yg    = (u16*)alloc((size_t)TSEQ * DIMM * 2);
  int*   segb  = (int*)alloc(256);
  u16*   Opart = (u16*)alloc((size_t)NH * NQB * NCMAX * QBLK * 128 * 2);
  float* Mp    = (float*)alloc((size_t)NH * NQB * NCMAX * QBLK * 4);
  float* Lp    = (float*)alloc((size_t)NH * NQB * NCMAX * QBLK * 4);

  k_convert<<<2048, 256, 0, stream>>>(x, qkvo, lam, xb, wb);
  k_gemm_nt<u16><<<dim3(24, 24), 256, 0, stream>>>(xb, wb, qkv, TSEQ, 3 * DIMM, DIMM);
  k_prep<<<dim3(TSEQ / 32, NH), 256, 0, stream>>>(qkv, x, ve, cosb, sinb, gwa, gwv, seg,
                                                  Qg, Kg, VTg, gateA, segb);
  k_attn<<<dim3(NH, NQB, NCMAX), 256, 0, stream>>>(Qg, Kg, VTg, segb, Opart, Mp, Lp);
  k_merge<<<dim3(NQB, NH), 256, 0, stream>>>(Opart, Mp, Lp, gateA, Yg);
  k_gemm_nt<float><<<dim3(DIMM / 128, 24), 256, 0, stream>>>(Yg, wb + (size_t)3 * DIMM * DIMM, out, TSEQ, DIMM, DIMM);
}